// Round 1
// 954.997 us; speedup vs baseline: 1.1131x; 1.1131x over previous
//
#include <hip/hip_runtime.h>

// Problem constants (B=4, L=4096, D=2048, DF=4*D=8192, k=L/2=2048)
#define BB 4
#define LL 4096
#define DD 2048
#define DFF 8192
#define KSEL 2048
#define MROWS (BB * KSEL)   // 8192 selected rows total

typedef __bf16 bf16x8 __attribute__((ext_vector_type(8)));
typedef float f32x4 __attribute__((ext_vector_type(4)));
typedef unsigned short u16x8 __attribute__((ext_vector_type(8)));

__device__ __forceinline__ unsigned short f2bf(float f) {
    union { float f; unsigned int u; } v; v.f = f;
    unsigned int u = v.u;
    unsigned int r = u + 0x7fffu + ((u >> 16) & 1u);   // RNE
    return (unsigned short)(r >> 16);
}

__device__ __forceinline__ void gl2lds16(const void* g, void* l) {
    __builtin_amdgcn_global_load_lds(
        (const __attribute__((address_space(1))) void*)g,
        (__attribute__((address_space(3))) void*)l,
        16, 0, 0);
}

// ---------------------------------------------------------------------------
// Router + bf16 conversion of ALL rows (fused; x is read once).
// ---------------------------------------------------------------------------
__global__ __launch_bounds__(256) void router_conv_kernel(
    const float* __restrict__ x, const float* __restrict__ wr,
    const float* __restrict__ br, float* __restrict__ scores,
    unsigned short* __restrict__ xbf)
{
    const int lane = threadIdx.x & 63;
    const int wave = threadIdx.x >> 6;
    const int tok = blockIdx.x * 4 + wave;         // [0, B*L)
    const float* row = x + (long)tok * DD;
    unsigned short* orow = xbf + (long)tok * DD;
    double acc = 0.0;
#pragma unroll
    for (int it = 0; it < 4; ++it) {
        const int off = it * 512 + lane * 8;
        float4 xv = *(const float4*)(row + off);
        float4 xw = *(const float4*)(row + off + 4);
        float4 wv = *(const float4*)(wr + off);
        float4 ww = *(const float4*)(wr + off + 4);
        acc += (double)xv.x * wv.x + (double)xv.y * wv.y
             + (double)xv.z * wv.z + (double)xv.w * wv.w;
        acc += (double)xw.x * ww.x + (double)xw.y * ww.y
             + (double)xw.z * ww.z + (double)xw.w * ww.w;
        u16x8 o;
        o[0] = f2bf(xv.x); o[1] = f2bf(xv.y); o[2] = f2bf(xv.z); o[3] = f2bf(xv.w);
        o[4] = f2bf(xw.x); o[5] = f2bf(xw.y); o[6] = f2bf(xw.z); o[7] = f2bf(xw.w);
        *(u16x8*)(orow + off) = o;
    }
#pragma unroll
    for (int o = 32; o > 0; o >>= 1) acc += __shfl_down(acc, o);
    if (lane == 0) scores[tok] = (float)(acc + (double)br[0]);
}

// ---------------------------------------------------------------------------
// Exact top-k membership by full rank count (tie-break: lower index wins).
// ---------------------------------------------------------------------------
__global__ __launch_bounds__(256) void rank_select_kernel(
    const float* __restrict__ scores, int* __restrict__ idxout,
    int* __restrict__ zidxout)
{
    __shared__ float s[LL];
    const int b = blockIdx.y;
    const float* sb = scores + b * LL;
    for (int i = threadIdx.x; i < LL; i += 256) s[i] = sb[i];
    __syncthreads();
    const int t = blockIdx.x * 256 + threadIdx.x;
    const float my = s[t];
    int rank = 0;
#pragma unroll 16
    for (int j = 0; j < LL; ++j) {
        float sj = s[j];
        rank += (sj > my) || (sj == my && j < t);
    }
    if (rank < KSEL) idxout[(b << 11) + rank] = t;
    else             zidxout[(b << 11) + rank - KSEL] = t;
}

// ---------------------------------------------------------------------------
// Zero the output rows of unselected tokens.
// ---------------------------------------------------------------------------
__global__ __launch_bounds__(256) void zero_rows_kernel(
    const int* __restrict__ zidx, float* __restrict__ Out)
{
    const int m = blockIdx.x;
    const int b = m >> 11;
    const int tok = zidx[m];
    float* dst = Out + ((long)b * LL + tok) * DD;
    const int c = threadIdx.x * 8;
    float4 z = {0.f, 0.f, 0.f, 0.f};
    *(float4*)(dst + c) = z;
    *(float4*)(dst + c + 4) = z;
}

// ---------------------------------------------------------------------------
// Convert+transpose BOTH weights in one launch.
// fp32 [KR][NC] -> bf16 [NC][KR], 64x64 tiles, 16B stores.
// ---------------------------------------------------------------------------
__global__ __launch_bounds__(256) void conv_transpose2_kernel(
    const float* __restrict__ W1, unsigned short* __restrict__ W1t,
    const float* __restrict__ W2, unsigned short* __restrict__ W2t)
{
    __shared__ unsigned short t[64 * 72];
    int bid = blockIdx.x;
    const float* W; unsigned short* Wt; int KR, NC, bx, by;
    if (bid < 4096) { W = W1; Wt = W1t; KR = DD; NC = DFF; bx = bid & 127; by = bid >> 7; }
    else { bid -= 4096; W = W2; Wt = W2t; KR = DFF; NC = DD; bx = bid & 31; by = bid >> 5; }
    const int n0 = bx * 64;
    const int k0 = by * 64;
    const int tid = threadIdx.x;
    const int rk = tid >> 4;                // 0..15
    const int cn = (tid & 15) * 4;          // 0..60
#pragma unroll
    for (int p = 0; p < 4; ++p) {
        const int k = rk + p * 16;
        float4 v = *(const float4*)(W + (long)(k0 + k) * NC + n0 + cn);
        t[(cn + 0) * 72 + k] = f2bf(v.x);
        t[(cn + 1) * 72 + k] = f2bf(v.y);
        t[(cn + 2) * 72 + k] = f2bf(v.z);
        t[(cn + 3) * 72 + k] = f2bf(v.w);
    }
    __syncthreads();
    const int rn = tid >> 3;                // 0..31
    const int ck = (tid & 7) * 8;           // 0..56
#pragma unroll
    for (int p = 0; p < 2; ++p) {
        const int n = rn + p * 32;
        u16x8 o = *(const u16x8*)&t[n * 72 + ck];
        *(u16x8*)(Wt + (long)(n0 + n) * KR + k0 + ck) = o;
    }
}

// ---------------------------------------------------------------------------
// Pipelined bf16 GEMM: C[M,N] = A[M,K] * Bt[N,K]^T (+bias/epilogue).
// 256x256 tile, BK=32, 8 waves (2M x 4N, 128x64 C per wave), 4-deep LDS ring
// (128 KiB), counted vmcnt(6), raw s_barrier, setprio around MFMA clusters,
// XOR-swizzled LDS (inverse-swizzled global source; swizzled ds_read),
// bijective XCD-chunked block mapping.
//
// Race-freedom: tile t lives in buf (t&3). Its B-unit is staged in phase 0
// of tile t-2, its A-unit in phase 1 of tile t-3; the previous occupant
// (tile t-4) had its last ds_read completed >= 2 barriers before either
// stage is issued. vmcnt(6) at the end of tile t forces tile t+1's 4 loads
// complete while leaving 3 units (6 loads) in flight — never drained to 0.
// ---------------------------------------------------------------------------
#define VM6 asm volatile("s_waitcnt vmcnt(6)" ::: "memory")
#define VM4 asm volatile("s_waitcnt vmcnt(4)" ::: "memory")
#define VM0 asm volatile("s_waitcnt vmcnt(0)" ::: "memory")
#define NOSTG ((void)0)
#define NOVM ((void)0)
#define CFENCE asm volatile("" ::: "memory")

#define STAGE_A(b, q, kt) gl2lds16(ga[q] + (kt), &As[b][(q) * 4096 + wave * 512])
#define STAGE_B(b, q, kt) gl2lds16(gb[q] + (kt), &Bs[b][(q) * 4096 + wave * 512])

// Phase 0 of a tile: read 4 A-frags (rows 0..63 of wave half) + 4 B-frags,
// issue one stage unit, optional vmcnt, barrier, 16 MFMA, barrier.
#define PH0(curb, STG, VMW) do {                                              \
    const char* ab_ = (const char*)&As[curb][0] + aoff;                       \
    const char* bb_ = (const char*)&Bs[curb][0] + boff;                       \
    bf16x8 af_[4];                                                            \
    _Pragma("unroll") for (int i_ = 0; i_ < 4; ++i_)                          \
        af_[i_] = *(const bf16x8*)(ab_ + i_ * 1024);                          \
    _Pragma("unroll") for (int j_ = 0; j_ < 4; ++j_)                          \
        bfr[j_] = *(const bf16x8*)(bb_ + j_ * 1024);                          \
    STG;                                                                      \
    VMW;                                                                      \
    CFENCE; __builtin_amdgcn_s_barrier(); CFENCE;                             \
    __builtin_amdgcn_s_setprio(1);                                            \
    _Pragma("unroll") for (int i_ = 0; i_ < 4; ++i_)                          \
        _Pragma("unroll") for (int j_ = 0; j_ < 4; ++j_)                      \
            acc[i_][j_] = __builtin_amdgcn_mfma_f32_16x16x32_bf16(            \
                af_[i_], bfr[j_], acc[i_][j_], 0, 0, 0);                      \
    __builtin_amdgcn_s_setprio(0);                                            \
    CFENCE; __builtin_amdgcn_s_barrier(); CFENCE;                             \
} while (0)

// Phase 1: rows 64..127 of the wave half; B-frags reused from registers.
#define PH1(curb, STG, VMW) do {                                              \
    const char* ab_ = (const char*)&As[curb][0] + aoff + 4096;                \
    bf16x8 af_[4];                                                            \
    _Pragma("unroll") for (int i_ = 0; i_ < 4; ++i_)                          \
        af_[i_] = *(const bf16x8*)(ab_ + i_ * 1024);                          \
    STG;                                                                      \
    VMW;                                                                      \
    CFENCE; __builtin_amdgcn_s_barrier(); CFENCE;                             \
    __builtin_amdgcn_s_setprio(1);                                            \
    _Pragma("unroll") for (int i_ = 0; i_ < 4; ++i_)                          \
        _Pragma("unroll") for (int j_ = 0; j_ < 4; ++j_)                      \
            acc[4 + i_][j_] = __builtin_amdgcn_mfma_f32_16x16x32_bf16(        \
                af_[i_], bfr[j_], acc[4 + i_][j_], 0, 0, 0);                  \
    __builtin_amdgcn_s_setprio(0);                                            \
    CFENCE; __builtin_amdgcn_s_barrier(); CFENCE;                             \
} while (0)

template <int MODE, int IND>
__global__ __launch_bounds__(512, 2) void gemm_pipe_kernel(
    const unsigned short* __restrict__ A,
    const unsigned short* __restrict__ Bt,
    const float* __restrict__ bias,
    unsigned short* __restrict__ H,
    const int* __restrict__ idx,
    float* __restrict__ Out,
    int K, int N)
{
    __shared__ unsigned short As[4][256 * 32];   // 4-deep ring, 16 KiB each
    __shared__ unsigned short Bs[4][256 * 32];   // total 128 KiB
    const int tid = threadIdx.x;
    const int lane = tid & 63;
    const int wave = tid >> 6;
    const int wm = wave >> 2;       // 0..1  (128 C-rows each)
    const int wn = wave & 3;        // 0..3  (64 C-cols each)

    // --- block mapping: bijective XCD chunking + 4-m-tile groups (T1) ---
    const int NN = N >> 8;                       // n-tiles
    const int nwg = (int)gridDim.x;              // multiple of 8
    const int per = nwg >> 3;
    const int wg = ((int)blockIdx.x & 7) * per + ((int)blockIdx.x >> 3);
    const int gsz = 4 * NN;                      // one group == one XCD share
    const int gidx = wg / gsz;
    const int rem = wg - gidx * gsz;
    const int pm = gidx * 4 + (rem & 3);
    const int pn = rem >> 2;
    const long m0 = (long)pm * 256;
    const long n0 = (long)pn * 256;

    // --- staging setup: thread covers chunks D = q*512 + tid of each tile.
    // LDS chunk D = (row r = D>>2, slot c = D&3) holds global k-chunk
    // c ^ (r&3) (inverse swizzle on the SOURCE; ds_read applies same XOR).
    const int cr = tid >> 2;                     // 0..127
    const int cl = (tid & 3) ^ (cr & 3);         // swizzled source k-chunk
    const unsigned short* ga[2];
    const unsigned short* gb[2];
#pragma unroll
    for (int q = 0; q < 2; ++q) {
        const int r = q * 128 + cr;              // tile row 0..255
        long ar;
        if constexpr (IND) {
            const int sel = (int)m0 + r;
            ar = (long)(sel >> 11) * LL + idx[sel];
        } else {
            ar = m0 + r;
        }
        ga[q] = A + ar * (long)K + cl * 8;
        gb[q] = Bt + (n0 + r) * (long)K + cl * 8;
    }

    // --- fragment read offsets (bytes), swizzled: row*64 + 16*(kc ^ (row&3))
    const int l15 = lane & 15;
    const int lg = lane >> 4;                    // k-group 0..3
    const int ko = ((lg ^ (l15 & 3)) << 4);
    const int aoff = (wm * 128 + l15) * 64 + ko;
    const int boff = (wn * 64 + l15) * 64 + ko;

    f32x4 acc[8][4];
#pragma unroll
    for (int i = 0; i < 8; ++i)
#pragma unroll
        for (int j = 0; j < 4; ++j) {
            f32x4 z = {0.f, 0.f, 0.f, 0.f};
            acc[i][j] = z;
        }
    bf16x8 bfr[4];

    const int NT = K >> 5;                       // BK=32 tiles (>= 64 here)

    // --- prologue: tiles 0,1 fully + A of tile 2 (5 units, 10 loads) ---
    STAGE_A(0, 0, 0);  STAGE_A(0, 1, 0);
    STAGE_B(0, 0, 0);  STAGE_B(0, 1, 0);
    STAGE_A(1, 0, 32); STAGE_A(1, 1, 32);
    STAGE_B(1, 0, 32); STAGE_B(1, 1, 32);
    STAGE_A(2, 0, 64); STAGE_A(2, 1, 64);
    VM6;                                          // tile 0 landed; 3 units fly
    CFENCE; __builtin_amdgcn_s_barrier(); CFENCE;

    // --- main loop: phase0 stages B(t+2), phase1 stages A(t+3) + vmcnt(6)
    int kb = 64, ka = 96;
    for (int t = 0; t < NT - 3; ++t) {
        const int cur = t & 3, b2 = (t + 2) & 3, b3 = (t + 3) & 3;
        PH0(cur, (STAGE_B(b2, 0, kb), STAGE_B(b2, 1, kb)), NOVM);
        PH1(cur, (STAGE_A(b3, 0, ka), STAGE_A(b3, 1, ka)), VM6);
        kb += 32; ka += 32;
    }
    {   // tile NT-3: last stage (B of tile NT-1), then vmcnt(4)
        const int cur = (NT - 3) & 3, b2 = (NT - 1) & 3;
        PH0(cur, (STAGE_B(b2, 0, kb), STAGE_B(b2, 1, kb)), NOVM);
        PH1(cur, NOSTG, VM4);
    }
    {   // tile NT-2: drain remaining loads
        const int cur = (NT - 2) & 3;
        PH0(cur, NOSTG, NOVM);
        PH1(cur, NOSTG, VM0);
    }
    {   // tile NT-1
        const int cur = (NT - 1) & 3;
        PH0(cur, NOSTG, NOVM);
        PH1(cur, NOSTG, NOVM);
    }

    // --- epilogue. C/D layout: col = lane&15, row = (lane>>4)*4 + reg ---
    if constexpr (MODE == 0) {
        const long rowb = m0 + wm * 128 + (lg << 2);
        const int colb = (int)n0 + wn * 64 + l15;
#pragma unroll
        for (int i = 0; i < 8; ++i) {
#pragma unroll
            for (int j = 0; j < 4; ++j) {
                const int col = colb + j * 16;
                const float bv = bias[col];
#pragma unroll
                for (int r = 0; r < 4; ++r) {
                    const long row = rowb + i * 16 + r;
                    float v = acc[i][j][r] + bv;
                    // tanh-gelu via exp: g = v - v/(1 + e^{1.5957691*u})
                    float u = v + 0.044715f * v * v * v;
                    float e = __expf(1.5957691216057308f * u);
                    float g = v - v * __builtin_amdgcn_rcpf(1.0f + e);
                    H[row * N + col] = f2bf(g);
                }
            }
        }
    } else {
        const int rowb = (int)m0 + wm * 128 + (lg << 2);
        const int colb = (int)n0 + wn * 64 + l15;
#pragma unroll
        for (int i = 0; i < 8; ++i) {
            int ob[4];
#pragma unroll
            for (int r = 0; r < 4; ++r) {
                const int row = rowb + i * 16 + r;
                const int b = row >> 11;
                const int tok = idx[(b << 11) + (row & (KSEL - 1))];
                ob[r] = (b * LL + tok) * DD;     // max ~33.5M, fits int
            }
#pragma unroll
            for (int j = 0; j < 4; ++j) {
                const int col = colb + j * 16;
                const float bv = bias[col];
#pragma unroll
                for (int r = 0; r < 4; ++r)
                    Out[(long)ob[r] + col] = acc[i][j][r] + bv;
            }
        }
    }
}

extern "C" void kernel_launch(void* const* d_in, const int* in_sizes, int n_in,
                              void* d_out, int out_size, void* d_ws, size_t ws_size,
                              hipStream_t stream)
{
    const float* x  = (const float*)d_in[0];   // [B,L,D]
    const float* wr = (const float*)d_in[1];   // [D]
    const float* br = (const float*)d_in[2];   // scalar
    const float* w1 = (const float*)d_in[3];   // [D,DF]
    const float* b1 = (const float*)d_in[4];   // [DF]
    const float* w2 = (const float*)d_in[5];   // [DF,D]
    const float* b2 = (const float*)d_in[6];   // [D]
    float* out = (float*)d_out;

    // Workspace carve-up (~290 MB total)
    char* ws = (char*)d_ws;
    float* scores = (float*)ws;              ws += (long)BB * LL * 4;          // 64 KB
    int* idx  = (int*)ws;                    ws += (long)BB * KSEL * 4;        // 32 KB
    int* zidx = (int*)ws;                    ws += (long)BB * (LL - KSEL) * 4; // 32 KB
    unsigned short* xbf  = (unsigned short*)ws; ws += (long)BB * LL * DD * 2;  // 64 MB
    unsigned short* w1t  = (unsigned short*)ws; ws += (long)DFF * DD * 2;      // 32 MB
    unsigned short* w2t  = (unsigned short*)ws; ws += (long)DD * DFF * 2;      // 32 MB
    unsigned short* h    = (unsigned short*)ws; ws += (long)MROWS * DFF * 2;   // 128 MB

    // 1) router scores (double accum) + bf16 conversion of all of x
    router_conv_kernel<<<(BB * LL) / 4, 256, 0, stream>>>(x, wr, br, scores, xbf);
    // 2) weights -> bf16 transposed (B^T layout), both in one launch
    conv_transpose2_kernel<<<8192, 256, 0, stream>>>(w1, w1t, w2, w2t);
    // 3) top-k membership + compaction (selected and unselected lists)
    rank_select_kernel<<<dim3(LL / 256, BB), 256, 0, stream>>>(scores, idx, zidx);
    // 4) zero only the unselected output rows
    zero_rows_kernel<<<BB * (LL - KSEL), 256, 0, stream>>>(zidx, out);
    // 5) h = bf16(gelu(gather(x)[idx] @ w1 + b1))  [8192 x 8192], K=2048
    gemm_pipe_kernel<0, 1><<<(MROWS / 256) * (DFF / 256), 512, 0, stream>>>(
        xbf, w1t, b1, h, idx, nullptr, DD, DFF);
    // 6) out[b, idx, :] = h @ w2 + b2 (scattered), K=8192
    gemm_pipe_kernel<1, 0><<<(MROWS / 256) * (DD / 256), 512, 0, stream>>>(
        h, w2t, b2, nullptr, idx, out, DFF, DD);
}